// Round 11
// baseline (293.215 us; speedup 1.0000x reference)
//
#include <hip/hip_runtime.h>
#include <stdint.h>

// GNN block: GCNConv(x@W, sym-norm agg w/ self loops) -> ReLU -> BatchNorm(train) -> JAX dropout
// R11: dispatch consolidation 11 -> 7: k_setup(wpack+zero), k_count(2 edges/thr),
//      k_scan(single-pass, last-block-finishes), k_gemm, k_fill(2 edges/thr),
//      k_agg(unchanged R10 form), k_bn(stats+reduce+finalize, acquire-spin, 256 blocks).
//      k_agg declared at ceiling (~40us): random-gather L3-path bound, FETCH pinned at 84MB.

#define NN 50000
#define NE 800000
#define DD 128
#define SCAN_B 256
#define NSB ((NN + SCAN_B - 1) / SCAN_B)   // 196
#define NSTAT 256                          // k_bn blocks (<= 256 CUs -> all resident)

using f32x4  = __attribute__((ext_vector_type(4))) float;
using short8 = __attribute__((ext_vector_type(8))) short;

// ---------------- threefry2x32 (JAX-compatible, partitionable path) ----------------
__device__ __forceinline__ uint32_t rotl32(uint32_t x, uint32_t d) {
  return (x << d) | (x >> (32u - d));
}

__device__ __forceinline__ uint32_t threefry_bits(uint32_t idx) {
  const uint32_t ks0 = 0u;
  const uint32_t ks1 = 42u;
  const uint32_t ks2 = 0x1BD11BDAu ^ ks0 ^ ks1;
  uint32_t x0 = ks0;
  uint32_t x1 = idx + ks1;
#define TF_R(r) { x0 += x1; x1 = rotl32(x1, (r)); x1 ^= x0; }
  TF_R(13u) TF_R(15u) TF_R(26u) TF_R(6u)
  x0 += ks1; x1 += ks2 + 1u;
  TF_R(17u) TF_R(29u) TF_R(16u) TF_R(24u)
  x0 += ks2; x1 += ks0 + 2u;
  TF_R(13u) TF_R(15u) TF_R(26u) TF_R(6u)
  x0 += ks0; x1 += ks1 + 3u;
  TF_R(17u) TF_R(29u) TF_R(16u) TF_R(24u)
  x0 += ks1; x1 += ks2 + 4u;
  TF_R(13u) TF_R(15u) TF_R(26u) TF_R(6u)
  x0 += ks2; x1 += ks0 + 5u;
#undef TF_R
  return x0 ^ x1;
}

__device__ __forceinline__ uint32_t f2bf(float f) {
  uint32_t u = __float_as_uint(f);
  return (u + 0x7fffu + ((u >> 16) & 1u)) >> 16;   // RNE
}
__device__ __forceinline__ float bf2f(uint32_t h) { return __uint_as_float(h << 16); }
__device__ __forceinline__ float bf_lo(uint32_t p) { return __uint_as_float(p << 16); }
__device__ __forceinline__ float bf_hi(uint32_t p) { return __uint_as_float(p & 0xffff0000u); }

// ---------------- setup: W pre-pack (blocks 0..7) + zero cnt/sync (blocks 8..) ----------------
__global__ __launch_bounds__(256) void k_setup(const float* __restrict__ Wm,
                                               short8* __restrict__ wfh,
                                               short8* __restrict__ wfl,
                                               int* __restrict__ cnt,
                                               int* __restrict__ sync) {
  int b = blockIdx.x;
  int t = threadIdx.x;
  if (b < 8) {
    int tid = b * 256 + t;               // 0..2047
    int lane = tid & 63;
    int cfks = tid >> 6;                 // ks = cfks>>3, cf = cfks&7
    int ks = cfks >> 3, cf = cfks & 7;
    int krow = ks * 32 + ((lane >> 4) << 3);
    int col = cf * 16 + (lane & 15);
    short8 h, l;
#pragma unroll
    for (int j = 0; j < 8; ++j) {
      float w = Wm[(size_t)(krow + j) * DD + col];
      uint32_t hb = f2bf(w);
      uint32_t lb = f2bf(w - bf2f(hb));
      h[j] = (short)hb;
      l[j] = (short)lb;
    }
    wfh[tid] = h;
    wfl[tid] = l;
  } else {
    int i = (b - 8) * 256 + t;
    if (i < NN) cnt[i] = 0;
    if (b == 8 && t < 4) sync[t] = 0;
  }
}

// ---------------- MFMA GEMM: hbf[N][128](bf16) = (x @ W) * dinv[row], hi/lo compensated ----
#define GBM 128
__global__ __launch_bounds__(256) void k_gemm(const float* __restrict__ x,
                                              const short8* __restrict__ wfh,
                                              const short8* __restrict__ wfl,
                                              const float* __restrict__ dinv,
                                              uint16_t* __restrict__ hbf) {
  __shared__ uint4 ldsbuf[4096];              // 64 KiB: xhi @0, xlo @32768
  char* lds = (char*)ldsbuf;
  const int t = threadIdx.x;
  const int row0 = blockIdx.x * GBM;
  const int c4 = t & 31, rbase = t >> 5;

#pragma unroll
  for (int i = 0; i < 16; ++i) {
    int r = rbase + i * 8;
    int grow = row0 + r;
    float4 v = make_float4(0.f, 0.f, 0.f, 0.f);
    if (grow < NN)
      v = *reinterpret_cast<const float4*>(&x[(size_t)grow * DD + c4 * 4]);
    uint32_t h0 = f2bf(v.x), h1 = f2bf(v.y), h2 = f2bf(v.z), h3 = f2bf(v.w);
    uint32_t l0 = f2bf(v.x - bf2f(h0)), l1 = f2bf(v.y - bf2f(h1));
    uint32_t l2 = f2bf(v.z - bf2f(h2)), l3 = f2bf(v.w - bf2f(h3));
    int byte = (r * 256 + c4 * 8) ^ ((r & 7) << 4);
    *reinterpret_cast<uint2*>(lds + byte) = make_uint2(h0 | (h1 << 16), h2 | (h3 << 16));
    *reinterpret_cast<uint2*>(lds + 32768 + byte) = make_uint2(l0 | (l1 << 16), l2 | (l3 << 16));
  }
  __syncthreads();

  const int wv = t >> 6, l = t & 63;
  f32x4 acc[2][8] = {};
#pragma unroll
  for (int ks = 0; ks < 4; ++ks) {
    short8 ah[2], al[2];
#pragma unroll
    for (int rf = 0; rf < 2; ++rf) {
      int r = wv * 32 + rf * 16 + (l & 15);
      int byte = (r * 256 + ks * 64 + ((l >> 4) << 4)) ^ ((r & 7) << 4);
      ah[rf] = *reinterpret_cast<const short8*>(lds + byte);
      al[rf] = *reinterpret_cast<const short8*>(lds + 32768 + byte);
    }
#pragma unroll
    for (int cf = 0; cf < 8; ++cf) {
      short8 bh = wfh[(ks * 8 + cf) * 64 + l];
      short8 bl = wfl[(ks * 8 + cf) * 64 + l];
#pragma unroll
      for (int rf = 0; rf < 2; ++rf) {
        acc[rf][cf] = __builtin_amdgcn_mfma_f32_16x16x32_bf16(ah[rf], bl, acc[rf][cf], 0, 0, 0);
        acc[rf][cf] = __builtin_amdgcn_mfma_f32_16x16x32_bf16(al[rf], bh, acc[rf][cf], 0, 0, 0);
        acc[rf][cf] = __builtin_amdgcn_mfma_f32_16x16x32_bf16(ah[rf], bh, acc[rf][cf], 0, 0, 0);
      }
    }
  }
  __syncthreads();   // reuse LDS for output repack

#pragma unroll
  for (int rf = 0; rf < 2; ++rf)
#pragma unroll
    for (int i = 0; i < 4; ++i) {
      int row = wv * 32 + rf * 16 + ((l >> 4) << 2) + i;
      int grow = row0 + row;
      float dv = (grow < NN) ? dinv[grow] : 0.f;
#pragma unroll
      for (int cf = 0; cf < 8; ++cf) {
        int col = cf * 16 + (l & 15);
        int byte = (row * 256 + col * 2) ^ ((row & 7) << 4);
        *reinterpret_cast<uint16_t*>(lds + byte) = (uint16_t)f2bf(acc[rf][cf][i] * dv);
      }
    }
  __syncthreads();
#pragma unroll
  for (int i = 0; i < 16; ++i) {
    int r = rbase + i * 8;
    int grow = row0 + r;
    if (grow < NN) {
      int byte = (r * 256 + c4 * 8) ^ ((r & 7) << 4);
      uint2 v = *reinterpret_cast<const uint2*>(lds + byte);
      *reinterpret_cast<uint2*>(&hbf[(size_t)grow * DD + c4 * 4]) = v;
    }
  }
}

// ---------------- degree count + slot assignment: 2 edges/thread ----------------
__global__ void k_count(const int* __restrict__ ei, int* __restrict__ cnt,
                        uint32_t* __restrict__ pos2) {
  int e2 = blockIdx.x * blockDim.x + threadIdx.x;
  int e = e2 * 2;
  if (e < NE) {
    int2 d = *reinterpret_cast<const int2*>(&ei[NE + e]);
    uint32_t p0 = (uint32_t)atomicAdd(&cnt[d.x], 1) & 0xffffu;
    uint32_t p1 = (uint32_t)atomicAdd(&cnt[d.y], 1) & 0xffffu;
    pos2[e2] = p0 | (p1 << 16);
  }
}

// ---------------- single-pass scan (last-block-finishes) + dinv ----------------
__global__ __launch_bounds__(SCAN_B) void k_scan(const int* __restrict__ cnt,
                                                 int* __restrict__ tmp,
                                                 int* __restrict__ blk_sums,
                                                 float* __restrict__ dinv,
                                                 int* __restrict__ row_ptr,
                                                 int* __restrict__ sync) {
  __shared__ int sm[SCAN_B];
  __shared__ int excl[SCAN_B];
  __shared__ int ticket_s;
  int t = threadIdx.x;
  int i = blockIdx.x * SCAN_B + t;
  int v = (i < NN) ? cnt[i] : 0;
  if (i < NN) dinv[i] = rsqrtf((float)v + 1.0f);
  sm[t] = v;
  __syncthreads();
  for (int off = 1; off < SCAN_B; off <<= 1) {
    int u = (t >= off) ? sm[t - off] : 0;
    __syncthreads();
    sm[t] += u;
    __syncthreads();
  }
  if (i < NN) tmp[i] = sm[t];
  if (t == SCAN_B - 1) blk_sums[blockIdx.x] = sm[t];
  __threadfence();                    // release our tmp/blk_sums writes
  __syncthreads();
  if (t == 0) ticket_s = atomicAdd(&sync[0], 1);
  __syncthreads();
  if (ticket_s != NSB - 1) return;    // all but the last-finisher exit

  // last block: all 196 blocks' writes are fenced-visible
  __threadfence();                    // acquire
  int bv = (t < NSB) ? blk_sums[t] : 0;
  __syncthreads();
  sm[t] = bv;
  __syncthreads();
  for (int off = 1; off < SCAN_B; off <<= 1) {
    int u = (t >= off) ? sm[t - off] : 0;
    __syncthreads();
    sm[t] += u;
    __syncthreads();
  }
  excl[t] = sm[t] - bv;
  __syncthreads();
  for (int base = 0; base < NN; base += SCAN_B) {
    int idx = base + t;
    if (idx < NN) row_ptr[idx + 1] = tmp[idx] + excl[idx >> 8];
  }
  if (t == 0) row_ptr[0] = 0;
}

// ---------------- CSR fill: 2 edges/thread, atomic-free, u16 colv ----------------
__global__ void k_fill(const int* __restrict__ ei, const int* __restrict__ row_ptr,
                       const uint32_t* __restrict__ pos2, uint16_t* __restrict__ colv) {
  int e2 = blockIdx.x * blockDim.x + threadIdx.x;
  int e = e2 * 2;
  if (e < NE) {
    int2 s = *reinterpret_cast<const int2*>(&ei[e]);
    int2 d = *reinterpret_cast<const int2*>(&ei[NE + e]);
    uint32_t pp = pos2[e2];
    colv[row_ptr[d.x] + (int)(pp & 0xffffu)] = (uint16_t)s.x;
    colv[row_ptr[d.y] + (int)(pp >> 16)]     = (uint16_t)s.y;
  }
}

// ---------------- aggregate: 16-batch -> 8-batch -> scalar tail (R10 form) ----------------
__global__ __launch_bounds__(256) void k_agg(const uint16_t* __restrict__ hbf,
                                             const int* __restrict__ row_ptr,
                                             const uint16_t* __restrict__ colv,
                                             const float* __restrict__ dinv,
                                             const float* __restrict__ bias,
                                             float* __restrict__ z) {
  int wave = threadIdx.x >> 6;
  int lane = threadIdx.x & 63;
  int node = blockIdx.x * 4 + wave;
  if (node >= NN) return;
  const uint32_t* hp = reinterpret_cast<const uint32_t*>(hbf);

  uint32_t ms = hp[(size_t)node * 64 + lane];
  float ax = bf_lo(ms), ay = bf_hi(ms);

  int e = row_ptr[node], end = row_ptr[node + 1];
  while (e + 16 <= end) {
    int s[16]; uint32_t m[16];
#pragma unroll
    for (int q = 0; q < 16; ++q) s[q] = colv[e + q];
#pragma unroll
    for (int q = 0; q < 16; ++q) m[q] = hp[(size_t)s[q] * 64 + lane];
#pragma unroll
    for (int q = 0; q < 16; ++q) {
      ax += bf_lo(m[q]);
      ay += bf_hi(m[q]);
    }
    e += 16;
  }
  while (e + 8 <= end) {
    int s[8]; uint32_t m[8];
#pragma unroll
    for (int q = 0; q < 8; ++q) s[q] = colv[e + q];
#pragma unroll
    for (int q = 0; q < 8; ++q) m[q] = hp[(size_t)s[q] * 64 + lane];
#pragma unroll
    for (int q = 0; q < 8; ++q) {
      ax += bf_lo(m[q]);
      ay += bf_hi(m[q]);
    }
    e += 8;
  }
  while (e < end) {
    uint32_t m0 = hp[(size_t)colv[e] * 64 + lane];
    ax += bf_lo(m0);
    ay += bf_hi(m0);
    ++e;
  }
  float di = dinv[node];
  float2 bb = reinterpret_cast<const float2*>(bias)[lane];
  float zx = fmaxf(fmaf(ax, di, bb.x), 0.f);
  float zy = fmaxf(fmaf(ay, di, bb.y), 0.f);
  reinterpret_cast<float2*>(z)[(size_t)node * 64 + lane] = make_float2(zx, zy);
}

// ---------------- fused BN: stats partials -> last-block reduce -> spin -> finalize ----------------
__global__ __launch_bounds__(256) void k_bn(float* __restrict__ z,
                                            float* __restrict__ part,
                                            float* __restrict__ bn_sum,
                                            float* __restrict__ bn_sumsq,
                                            const float* __restrict__ gamma,
                                            const float* __restrict__ beta,
                                            int* __restrict__ sync) {
  int t = threadIdx.x;
  // ---- phase 1: per-block channel partials (no atomics) ----
  {
    int c4 = t & 31;
    int rgrp = t >> 5;
    float sx = 0.f, sy = 0.f, sz = 0.f, sw = 0.f;
    float qx = 0.f, qy = 0.f, qz = 0.f, qw = 0.f;
    for (int r = blockIdx.x * 8 + rgrp; r < NN; r += NSTAT * 8) {
      float4 v = *reinterpret_cast<const float4*>(&z[(size_t)r * DD + c4 * 4]);
      sx += v.x; sy += v.y; sz += v.z; sw += v.w;
      qx = fmaf(v.x, v.x, qx); qy = fmaf(v.y, v.y, qy);
      qz = fmaf(v.z, v.z, qz); qw = fmaf(v.w, v.w, qw);
    }
    __shared__ float sm[2048], sm2[2048];
    sm[t * 4 + 0] = sx; sm[t * 4 + 1] = sy; sm[t * 4 + 2] = sz; sm[t * 4 + 3] = sw;
    sm2[t * 4 + 0] = qx; sm2[t * 4 + 1] = qy; sm2[t * 4 + 2] = qz; sm2[t * 4 + 3] = qw;
    __syncthreads();
    int c = t & 127;
    float acc = 0.f;
    if (t < 128) {
#pragma unroll
      for (int g = 0; g < 8; ++g) acc += sm[g * 128 + c];
    } else {
#pragma unroll
      for (int g = 0; g < 8; ++g) acc += sm2[g * 128 + c];
    }
    part[blockIdx.x * 256 + t] = acc;
  }
  __threadfence();                       // release partials
  __syncthreads();
  __shared__ int ticket_s;
  if (t == 0) ticket_s = atomicAdd(&sync[1], 1);
  __syncthreads();
  if (ticket_s == NSTAT - 1) {
    // ---- phase 1.5: last block reduces all partials ----
    __threadfence();                     // acquire partials
    float a = 0.f;
    for (int b = 0; b < NSTAT; ++b) a += part[b * 256 + t];
    if (t < 128) bn_sum[t] = a;
    else bn_sumsq[t - 128] = a;
    __threadfence();                     // release bn stats
    __syncthreads();
    if (t == 0) atomicExch(&sync[2], 1);
  } else {
    if (t == 0) {
      while (__hip_atomic_load(&sync[2], __ATOMIC_ACQUIRE, __HIP_MEMORY_SCOPE_AGENT) == 0)
        __builtin_amdgcn_s_sleep(10);
    }
    __syncthreads();
  }
  __threadfence();                       // acquire bn stats on all blocks

  // ---- phase 2: BN + dropout finalize, grid-stride float4 ----
  const float invN = 1.0f / (float)NN;
  int c4p = -1;
  float mm[4], rr[4], gg[4], bb[4];
  for (int j4 = blockIdx.x * 256 + t; j4 < NN * DD / 4; j4 += NSTAT * 256) {
    int c4 = j4 & 31;
    if (c4 != c4p) {                     // per-thread channel params are loop-invariant mod 32
      c4p = c4;
      float4 s = *reinterpret_cast<const float4*>(&bn_sum[c4 * 4]);
      float4 q = *reinterpret_cast<const float4*>(&bn_sumsq[c4 * 4]);
      float4 g = *reinterpret_cast<const float4*>(&gamma[c4 * 4]);
      float4 bt = *reinterpret_cast<const float4*>(&beta[c4 * 4]);
      float sv[4] = {s.x, s.y, s.z, s.w};
      float qv[4] = {q.x, q.y, q.z, q.w};
      float gv[4] = {g.x, g.y, g.z, g.w};
      float bv[4] = {bt.x, bt.y, bt.z, bt.w};
#pragma unroll
      for (int i = 0; i < 4; ++i) {
        mm[i] = sv[i] * invN;
        float var = qv[i] * invN - mm[i] * mm[i];
        rr[i] = rsqrtf(var + 1e-5f) * gv[i];
        bb[i] = bv[i];
        gg[i] = 0.f; (void)gg;
      }
    }
    float4 v = *reinterpret_cast<const float4*>(&z[(size_t)j4 * 4]);
    float vv[4] = {v.x, v.y, v.z, v.w};
    float out[4];
#pragma unroll
    for (int i = 0; i < 4; ++i) {
      float val = (vv[i] - mm[i]) * rr[i] + bb[i];
      uint32_t bits = threefry_bits((uint32_t)(j4 * 4 + i));
      float u = __uint_as_float((bits >> 9) | 0x3f800000u) - 1.0f;
      out[i] = (u < 0.9f) ? val * (1.0f / 0.9f) : 0.0f;
    }
    *reinterpret_cast<float4*>(&z[(size_t)j4 * 4]) = make_float4(out[0], out[1], out[2], out[3]);
  }
}

// ---------------- launch ----------------
extern "C" void kernel_launch(void* const* d_in, const int* in_sizes, int n_in,
                              void* d_out, int out_size, void* d_ws, size_t ws_size,
                              hipStream_t stream) {
  const float* x     = (const float*)d_in[0];
  const int*   ei    = (const int*)d_in[1];
  const float* Wm    = (const float*)d_in[2];
  const float* bvec  = (const float*)d_in[3];
  const float* gamma = (const float*)d_in[4];
  const float* beta  = (const float*)d_in[5];
  float* zout = (float*)d_out;

  // workspace layout
  uint16_t* hbf  = (uint16_t*)d_ws;                         // NN*DD bf16 (12.8MB)
  short8* wfh    = (short8*)(hbf + (size_t)NN * DD);        // 32KB
  short8* wfl    = wfh + 2048;                              // 32KB
  uint16_t* colv = (uint16_t*)(wfl + 2048);                 // NE u16
  uint32_t* pos2 = (uint32_t*)(colv + NE);                  // NE/2 u32 (packed u16 pairs)
  int* cnt       = (int*)(pos2 + NE / 2);                   // NN (zeroed by k_setup)
  float* bn_sum  = (float*)(cnt + NN);                      // DD
  float* bn_sumsq= bn_sum + DD;                             // DD
  int* tmp_scan  = (int*)(bn_sumsq + DD);                   // NN
  int* row_ptr   = tmp_scan + NN;                           // NN+1
  float* dinv    = (float*)(row_ptr + NN + 1);              // NN
  int* blk_sums  = (int*)(dinv + NN);                       // NSB
  float* part    = (float*)(blk_sums + NSB);                // NSTAT*256
  int* sync      = (int*)(part + NSTAT * 256);              // 4 (zeroed by k_setup)

  k_setup<<<8 + NSB, 256, 0, stream>>>(Wm, wfh, wfl, cnt, sync);
  k_count<<<(NE / 2 + 255) / 256, 256, 0, stream>>>(ei, cnt, pos2);
  k_scan<<<NSB, SCAN_B, 0, stream>>>(cnt, tmp_scan, blk_sums, dinv, row_ptr, sync);
  k_gemm<<<(NN + GBM - 1) / GBM, 256, 0, stream>>>(x, wfh, wfl, dinv, hbf);
  k_fill<<<(NE / 2 + 255) / 256, 256, 0, stream>>>(ei, row_ptr, pos2, colv);
  k_agg<<<(NN + 3) / 4, 256, 0, stream>>>(hbf, row_ptr, colv, dinv, bvec, zout);
  k_bn<<<NSTAT, 256, 0, stream>>>(zout, part, bn_sum, bn_sumsq, gamma, beta, sync);
}

// Round 12
// 160.544 us; speedup vs baseline: 1.8264x; 1.8264x over previous
//
#include <hip/hip_runtime.h>
#include <stdint.h>

// GNN block: GCNConv(x@W, sym-norm agg w/ self loops) -> ReLU -> BatchNorm(train) -> JAX dropout
// R12: revert R11's fused k_bn (spin-sync forced 256-block grid -> 11% occupancy -> 130us
//      memory sweep; fusion via device sync trades away occupancy). Back to R10 structure:
//      scan1+scan3, k_stats@400 (no atomics) + k_stats2 + k_final@full grid.
//      Kept from R11: 2-edges/thread k_count & k_fill with packed u16 pos (int2 edge loads).
//      k_agg at its ceiling (~40us, random-gather L3-path bound, FETCH pinned 84MB).

#define NN 50000
#define NE 800000
#define DD 128
#define SCAN_B 256
#define NSB ((NN + SCAN_B - 1) / SCAN_B)   // 196
#define NSTAT 400                          // k_stats blocks

using f32x4  = __attribute__((ext_vector_type(4))) float;
using short8 = __attribute__((ext_vector_type(8))) short;

// ---------------- threefry2x32 (JAX-compatible, partitionable path) ----------------
__device__ __forceinline__ uint32_t rotl32(uint32_t x, uint32_t d) {
  return (x << d) | (x >> (32u - d));
}

__device__ __forceinline__ uint32_t threefry_bits(uint32_t idx) {
  const uint32_t ks0 = 0u;
  const uint32_t ks1 = 42u;
  const uint32_t ks2 = 0x1BD11BDAu ^ ks0 ^ ks1;
  uint32_t x0 = ks0;
  uint32_t x1 = idx + ks1;
#define TF_R(r) { x0 += x1; x1 = rotl32(x1, (r)); x1 ^= x0; }
  TF_R(13u) TF_R(15u) TF_R(26u) TF_R(6u)
  x0 += ks1; x1 += ks2 + 1u;
  TF_R(17u) TF_R(29u) TF_R(16u) TF_R(24u)
  x0 += ks2; x1 += ks0 + 2u;
  TF_R(13u) TF_R(15u) TF_R(26u) TF_R(6u)
  x0 += ks0; x1 += ks1 + 3u;
  TF_R(17u) TF_R(29u) TF_R(16u) TF_R(24u)
  x0 += ks1; x1 += ks2 + 4u;
  TF_R(13u) TF_R(15u) TF_R(26u) TF_R(6u)
  x0 += ks2; x1 += ks0 + 5u;
#undef TF_R
  return x0 ^ x1;
}

__device__ __forceinline__ uint32_t f2bf(float f) {
  uint32_t u = __float_as_uint(f);
  return (u + 0x7fffu + ((u >> 16) & 1u)) >> 16;   // RNE
}
__device__ __forceinline__ float bf2f(uint32_t h) { return __uint_as_float(h << 16); }
__device__ __forceinline__ float bf_lo(uint32_t p) { return __uint_as_float(p << 16); }
__device__ __forceinline__ float bf_hi(uint32_t p) { return __uint_as_float(p & 0xffff0000u); }

// ---------------- W pre-pack into MFMA fragment order ----------------
__global__ __launch_bounds__(256) void k_wpack(const float* __restrict__ Wm,
                                               short8* __restrict__ wfh,
                                               short8* __restrict__ wfl) {
  int tid = blockIdx.x * 256 + threadIdx.x;   // 0..2047
  if (tid >= 32 * 64) return;
  int lane = tid & 63;
  int cfks = tid >> 6;        // ks = cfks>>3, cf = cfks&7
  int ks = cfks >> 3, cf = cfks & 7;
  int krow = ks * 32 + ((lane >> 4) << 3);
  int col = cf * 16 + (lane & 15);
  short8 h, l;
#pragma unroll
  for (int j = 0; j < 8; ++j) {
    float w = Wm[(size_t)(krow + j) * DD + col];
    uint32_t hb = f2bf(w);
    uint32_t lb = f2bf(w - bf2f(hb));
    h[j] = (short)hb;
    l[j] = (short)lb;
  }
  wfh[tid] = h;
  wfl[tid] = l;
}

// ---------------- MFMA GEMM: hbf[N][128](bf16) = (x @ W) * dinv[row], hi/lo compensated ----
#define GBM 128
__global__ __launch_bounds__(256) void k_gemm(const float* __restrict__ x,
                                              const short8* __restrict__ wfh,
                                              const short8* __restrict__ wfl,
                                              const float* __restrict__ dinv,
                                              uint16_t* __restrict__ hbf) {
  __shared__ uint4 ldsbuf[4096];              // 64 KiB: xhi @0, xlo @32768
  char* lds = (char*)ldsbuf;
  const int t = threadIdx.x;
  const int row0 = blockIdx.x * GBM;
  const int c4 = t & 31, rbase = t >> 5;

#pragma unroll
  for (int i = 0; i < 16; ++i) {
    int r = rbase + i * 8;
    int grow = row0 + r;
    float4 v = make_float4(0.f, 0.f, 0.f, 0.f);
    if (grow < NN)
      v = *reinterpret_cast<const float4*>(&x[(size_t)grow * DD + c4 * 4]);
    uint32_t h0 = f2bf(v.x), h1 = f2bf(v.y), h2 = f2bf(v.z), h3 = f2bf(v.w);
    uint32_t l0 = f2bf(v.x - bf2f(h0)), l1 = f2bf(v.y - bf2f(h1));
    uint32_t l2 = f2bf(v.z - bf2f(h2)), l3 = f2bf(v.w - bf2f(h3));
    int byte = (r * 256 + c4 * 8) ^ ((r & 7) << 4);
    *reinterpret_cast<uint2*>(lds + byte) = make_uint2(h0 | (h1 << 16), h2 | (h3 << 16));
    *reinterpret_cast<uint2*>(lds + 32768 + byte) = make_uint2(l0 | (l1 << 16), l2 | (l3 << 16));
  }
  __syncthreads();

  const int wv = t >> 6, l = t & 63;
  f32x4 acc[2][8] = {};
#pragma unroll
  for (int ks = 0; ks < 4; ++ks) {
    short8 ah[2], al[2];
#pragma unroll
    for (int rf = 0; rf < 2; ++rf) {
      int r = wv * 32 + rf * 16 + (l & 15);
      int byte = (r * 256 + ks * 64 + ((l >> 4) << 4)) ^ ((r & 7) << 4);
      ah[rf] = *reinterpret_cast<const short8*>(lds + byte);
      al[rf] = *reinterpret_cast<const short8*>(lds + 32768 + byte);
    }
#pragma unroll
    for (int cf = 0; cf < 8; ++cf) {
      short8 bh = wfh[(ks * 8 + cf) * 64 + l];
      short8 bl = wfl[(ks * 8 + cf) * 64 + l];
#pragma unroll
      for (int rf = 0; rf < 2; ++rf) {
        acc[rf][cf] = __builtin_amdgcn_mfma_f32_16x16x32_bf16(ah[rf], bl, acc[rf][cf], 0, 0, 0);
        acc[rf][cf] = __builtin_amdgcn_mfma_f32_16x16x32_bf16(al[rf], bh, acc[rf][cf], 0, 0, 0);
        acc[rf][cf] = __builtin_amdgcn_mfma_f32_16x16x32_bf16(ah[rf], bh, acc[rf][cf], 0, 0, 0);
      }
    }
  }
  __syncthreads();   // reuse LDS for output repack

#pragma unroll
  for (int rf = 0; rf < 2; ++rf)
#pragma unroll
    for (int i = 0; i < 4; ++i) {
      int row = wv * 32 + rf * 16 + ((l >> 4) << 2) + i;
      int grow = row0 + row;
      float dv = (grow < NN) ? dinv[grow] : 0.f;
#pragma unroll
      for (int cf = 0; cf < 8; ++cf) {
        int col = cf * 16 + (l & 15);
        int byte = (row * 256 + col * 2) ^ ((row & 7) << 4);
        *reinterpret_cast<uint16_t*>(lds + byte) = (uint16_t)f2bf(acc[rf][cf][i] * dv);
      }
    }
  __syncthreads();
#pragma unroll
  for (int i = 0; i < 16; ++i) {
    int r = rbase + i * 8;
    int grow = row0 + r;
    if (grow < NN) {
      int byte = (r * 256 + c4 * 8) ^ ((r & 7) << 4);
      uint2 v = *reinterpret_cast<const uint2*>(lds + byte);
      *reinterpret_cast<uint2*>(&hbf[(size_t)grow * DD + c4 * 4]) = v;
    }
  }
}

// ---------------- degree count + slot assignment: 2 edges/thread, packed u16 pos ----------------
__global__ void k_count(const int* __restrict__ ei, int* __restrict__ cnt,
                        uint32_t* __restrict__ pos2) {
  int e2 = blockIdx.x * blockDim.x + threadIdx.x;
  int e = e2 * 2;
  if (e < NE) {
    int2 d = *reinterpret_cast<const int2*>(&ei[NE + e]);
    uint32_t p0 = (uint32_t)atomicAdd(&cnt[d.x], 1) & 0xffffu;
    uint32_t p1 = (uint32_t)atomicAdd(&cnt[d.y], 1) & 0xffffu;
    pos2[e2] = p0 | (p1 << 16);
  }
}

// ---------------- scan stage 1: block-inclusive scan + dinv ----------------
__global__ __launch_bounds__(SCAN_B) void k_scan1(const int* __restrict__ cnt,
                                                  int* __restrict__ tmp,
                                                  int* __restrict__ blk_sums,
                                                  float* __restrict__ dinv) {
  __shared__ int sm[SCAN_B];
  int t = threadIdx.x;
  int i = blockIdx.x * SCAN_B + t;
  int v = (i < NN) ? cnt[i] : 0;
  if (i < NN) dinv[i] = rsqrtf((float)v + 1.0f);
  sm[t] = v;
  __syncthreads();
  for (int off = 1; off < SCAN_B; off <<= 1) {
    int u = (t >= off) ? sm[t - off] : 0;
    __syncthreads();
    sm[t] += u;
    __syncthreads();
  }
  if (i < NN) tmp[i] = sm[t];
  if (t == SCAN_B - 1) blk_sums[blockIdx.x] = sm[t];
}

// ---------------- scan stage 3: row_ptr (block-offset recomputed locally) ----------------
__global__ __launch_bounds__(SCAN_B) void k_scan3(const int* __restrict__ tmp,
                                                  const int* __restrict__ blk_sums,
                                                  int* __restrict__ row_ptr) {
  __shared__ int sm[SCAN_B];
  int t = threadIdx.x;
  int v = (t < NSB) ? blk_sums[t] : 0;
  sm[t] = v;
  __syncthreads();
  for (int off = 1; off < SCAN_B; off <<= 1) {
    int u = (t >= off) ? sm[t - off] : 0;
    __syncthreads();
    sm[t] += u;
    __syncthreads();
  }
  int excl = sm[blockIdx.x] - blk_sums[blockIdx.x];
  int i = blockIdx.x * SCAN_B + t;
  if (i < NN) {
    row_ptr[i + 1] = tmp[i] + excl;
    if (i == 0) row_ptr[0] = 0;
  }
}

// ---------------- CSR fill: 2 edges/thread, atomic-free, u16 colv ----------------
__global__ void k_fill(const int* __restrict__ ei, const int* __restrict__ row_ptr,
                       const uint32_t* __restrict__ pos2, uint16_t* __restrict__ colv) {
  int e2 = blockIdx.x * blockDim.x + threadIdx.x;
  int e = e2 * 2;
  if (e < NE) {
    int2 s = *reinterpret_cast<const int2*>(&ei[e]);
    int2 d = *reinterpret_cast<const int2*>(&ei[NE + e]);
    uint32_t pp = pos2[e2];
    colv[row_ptr[d.x] + (int)(pp & 0xffffu)] = (uint16_t)s.x;
    colv[row_ptr[d.y] + (int)(pp >> 16)]     = (uint16_t)s.y;
  }
}

// ---------------- aggregate: 16-batch -> 8-batch -> scalar tail (R10 form, at ceiling) ----------------
__global__ __launch_bounds__(256) void k_agg(const uint16_t* __restrict__ hbf,
                                             const int* __restrict__ row_ptr,
                                             const uint16_t* __restrict__ colv,
                                             const float* __restrict__ dinv,
                                             const float* __restrict__ bias,
                                             float* __restrict__ z) {
  int wave = threadIdx.x >> 6;
  int lane = threadIdx.x & 63;
  int node = blockIdx.x * 4 + wave;
  if (node >= NN) return;
  const uint32_t* hp = reinterpret_cast<const uint32_t*>(hbf);

  uint32_t ms = hp[(size_t)node * 64 + lane];
  float ax = bf_lo(ms), ay = bf_hi(ms);

  int e = row_ptr[node], end = row_ptr[node + 1];
  while (e + 16 <= end) {
    int s[16]; uint32_t m[16];
#pragma unroll
    for (int q = 0; q < 16; ++q) s[q] = colv[e + q];
#pragma unroll
    for (int q = 0; q < 16; ++q) m[q] = hp[(size_t)s[q] * 64 + lane];
#pragma unroll
    for (int q = 0; q < 16; ++q) {
      ax += bf_lo(m[q]);
      ay += bf_hi(m[q]);
    }
    e += 16;
  }
  while (e + 8 <= end) {
    int s[8]; uint32_t m[8];
#pragma unroll
    for (int q = 0; q < 8; ++q) s[q] = colv[e + q];
#pragma unroll
    for (int q = 0; q < 8; ++q) m[q] = hp[(size_t)s[q] * 64 + lane];
#pragma unroll
    for (int q = 0; q < 8; ++q) {
      ax += bf_lo(m[q]);
      ay += bf_hi(m[q]);
    }
    e += 8;
  }
  while (e < end) {
    uint32_t m0 = hp[(size_t)colv[e] * 64 + lane];
    ax += bf_lo(m0);
    ay += bf_hi(m0);
    ++e;
  }
  float di = dinv[node];
  float2 bb = reinterpret_cast<const float2*>(bias)[lane];
  float zx = fmaxf(fmaf(ax, di, bb.x), 0.f);
  float zy = fmaxf(fmaf(ay, di, bb.y), 0.f);
  reinterpret_cast<float2*>(z)[(size_t)node * 64 + lane] = make_float2(zx, zy);
}

// ---------------- BN stats stage 1: per-block partials, NO atomics ----------------
__global__ __launch_bounds__(256) void k_stats(const float* __restrict__ z,
                                               float* __restrict__ part) {
  int t = threadIdx.x;
  int c4 = t & 31;
  int rgrp = t >> 5;
  float sx = 0.f, sy = 0.f, sz = 0.f, sw = 0.f;
  float qx = 0.f, qy = 0.f, qz = 0.f, qw = 0.f;
  for (int r = blockIdx.x * 8 + rgrp; r < NN; r += NSTAT * 8) {
    float4 v = *reinterpret_cast<const float4*>(&z[(size_t)r * DD + c4 * 4]);
    sx += v.x; sy += v.y; sz += v.z; sw += v.w;
    qx = fmaf(v.x, v.x, qx); qy = fmaf(v.y, v.y, qy);
    qz = fmaf(v.z, v.z, qz); qw = fmaf(v.w, v.w, qw);
  }
  __shared__ float sm[2048], sm2[2048];
  sm[t * 4 + 0] = sx; sm[t * 4 + 1] = sy; sm[t * 4 + 2] = sz; sm[t * 4 + 3] = sw;
  sm2[t * 4 + 0] = qx; sm2[t * 4 + 1] = qy; sm2[t * 4 + 2] = qz; sm2[t * 4 + 3] = qw;
  __syncthreads();
  int c = t & 127;
  float acc = 0.f;
  if (t < 128) {
#pragma unroll
    for (int g = 0; g < 8; ++g) acc += sm[g * 128 + c];
  } else {
#pragma unroll
    for (int g = 0; g < 8; ++g) acc += sm2[g * 128 + c];
  }
  part[blockIdx.x * 256 + t] = acc;
}

// ---------------- BN stats stage 2: reduce partials (1 block) ----------------
__global__ __launch_bounds__(256) void k_stats2(const float* __restrict__ part,
                                                float* __restrict__ bn_sum,
                                                float* __restrict__ bn_sumsq) {
  int t = threadIdx.x;
  float acc = 0.f;
  for (int b = 0; b < NSTAT; ++b) acc += part[b * 256 + t];
  if (t < 128) bn_sum[t] = acc;
  else bn_sumsq[t - 128] = acc;
}

// ---------------- finalize: BN + dropout (float4 per thread, full grid) ----------------
__global__ __launch_bounds__(256) void k_final(float* __restrict__ z,
                                               const float* __restrict__ bn_sum,
                                               const float* __restrict__ bn_sumsq,
                                               const float* __restrict__ gamma,
                                               const float* __restrict__ beta) {
  int j4 = blockIdx.x * blockDim.x + threadIdx.x;
  if (j4 >= NN * DD / 4) return;
  int c4 = j4 & 31;
  const float invN = 1.0f / (float)NN;
  float4 s = *reinterpret_cast<const float4*>(&bn_sum[c4 * 4]);
  float4 q = *reinterpret_cast<const float4*>(&bn_sumsq[c4 * 4]);
  float4 g = *reinterpret_cast<const float4*>(&gamma[c4 * 4]);
  float4 bt = *reinterpret_cast<const float4*>(&beta[c4 * 4]);
  float4 v = *reinterpret_cast<const float4*>(&z[(size_t)j4 * 4]);
  float out[4];
  float mm[4] = {s.x * invN, s.y * invN, s.z * invN, s.w * invN};
  float qq[4] = {q.x * invN, q.y * invN, q.z * invN, q.w * invN};
  float gg[4] = {g.x, g.y, g.z, g.w};
  float bb[4] = {bt.x, bt.y, bt.z, bt.w};
  float vv[4] = {v.x, v.y, v.z, v.w};
#pragma unroll
  for (int i = 0; i < 4; ++i) {
    float var = qq[i] - mm[i] * mm[i];
    float rs = rsqrtf(var + 1e-5f);
    float val = (vv[i] - mm[i]) * rs * gg[i] + bb[i];
    uint32_t bits = threefry_bits((uint32_t)(j4 * 4 + i));
    float u = __uint_as_float((bits >> 9) | 0x3f800000u) - 1.0f;
    out[i] = (u < 0.9f) ? val * (1.0f / 0.9f) : 0.0f;
  }
  *reinterpret_cast<float4*>(&z[(size_t)j4 * 4]) = make_float4(out[0], out[1], out[2], out[3]);
}

// ---------------- launch ----------------
extern "C" void kernel_launch(void* const* d_in, const int* in_sizes, int n_in,
                              void* d_out, int out_size, void* d_ws, size_t ws_size,
                              hipStream_t stream) {
  const float* x     = (const float*)d_in[0];
  const int*   ei    = (const int*)d_in[1];
  const float* Wm    = (const float*)d_in[2];
  const float* bvec  = (const float*)d_in[3];
  const float* gamma = (const float*)d_in[4];
  const float* beta  = (const float*)d_in[5];
  float* zout = (float*)d_out;

  // workspace layout
  uint16_t* hbf  = (uint16_t*)d_ws;                         // NN*DD bf16 (12.8MB)
  short8* wfh    = (short8*)(hbf + (size_t)NN * DD);        // 32KB
  short8* wfl    = wfh + 2048;                              // 32KB
  uint16_t* colv = (uint16_t*)(wfl + 2048);                 // NE u16
  uint32_t* pos2 = (uint32_t*)(colv + NE);                  // NE/2 u32 (packed u16 pairs)
  int* cnt       = (int*)(pos2 + NE / 2);                   // NN (zeroed)
  float* bn_sum  = (float*)(cnt + NN);                      // DD
  float* bn_sumsq= bn_sum + DD;                             // DD
  int* tmp_scan  = (int*)(bn_sumsq + DD);                   // NN
  int* row_ptr   = tmp_scan + NN;                           // NN+1
  float* dinv    = (float*)(row_ptr + NN + 1);              // NN
  int* blk_sums  = (int*)(dinv + NN);                       // NSB
  float* part    = (float*)(blk_sums + NSB);                // NSTAT*256

  hipMemsetAsync(cnt, 0, (size_t)NN * sizeof(int), stream);

  k_wpack<<<8, 256, 0, stream>>>(Wm, wfh, wfl);
  k_count<<<(NE / 2 + 255) / 256, 256, 0, stream>>>(ei, cnt, pos2);
  k_scan1<<<NSB, SCAN_B, 0, stream>>>(cnt, tmp_scan, blk_sums, dinv);
  k_scan3<<<NSB, SCAN_B, 0, stream>>>(tmp_scan, blk_sums, row_ptr);
  k_gemm<<<(NN + GBM - 1) / GBM, 256, 0, stream>>>(x, wfh, wfl, dinv, hbf);
  k_fill<<<(NE / 2 + 255) / 256, 256, 0, stream>>>(ei, row_ptr, pos2, colv);
  k_agg<<<(NN + 3) / 4, 256, 0, stream>>>(hbf, row_ptr, colv, dinv, bvec, zout);
  k_stats<<<NSTAT, 256, 0, stream>>>(zout, part);
  k_stats2<<<1, 256, 0, stream>>>(part, bn_sum, bn_sumsq);
  k_final<<<(NN * DD / 4 + 255) / 256, 256, 0, stream>>>(zout, bn_sum, bn_sumsq, gamma, beta);
}